// Round 6
// baseline (3799.424 us; speedup 1.0000x reference)
//
#include <hip/hip_runtime.h>
#include <stdint.h>

// GNNCell: 2x SAGEConv(lstm) + 2 MLP heads. N=100000, D=16, H=128, fp32 I/O.
// R12 passed 2920 us (lstm 2x1155, WRITE 78MB, no spill; heads fused OK).
//     VALU 40.4 > MFMA 25.1 > HBM 14.7; occ 21% (2 waves/SIMD, Whh in AGPRs).
//     VALU breakdown: X unpack (fp16+i8 -> f32) = ~320 ops/step/lane = 34%
//     of VALU; memory has 6x headroom -> flip the tradeoff.
// R13: X stored fp32 (204.8 MB), j-group-interleaved layout
//     [node][(j>>2)*16 + g*4 + (j&3)]: per lane/nt ONE contiguous 64B run
//     (4x dwordx4) covering all 4 gates. Unpack -> 16 v_add_f32/nt.
//     Register discipline (R10 spill lesson): X regs 48->32 via xA/xB
//     double-buffer, loads re-issued right after consumption (>=600cyc
//     issue->use). Whh/pack paths byte-identical to R12 (f2b only, no asm).
//     ws_size >= 204.8MB checked at launch; else fall back to R12 path.
// Precision: X now exact fp32 (was 2^-15 quantized) - strictly better.

typedef __attribute__((ext_vector_type(8))) short short8_t;
typedef __attribute__((ext_vector_type(4))) float float4_t;
typedef __attribute__((ext_vector_type(4))) unsigned uint4_t;
typedef _Float16 half8_t __attribute__((ext_vector_type(8)));

#define NNODES 100000
#define DNB 16
#define LOSCALE 32768.0f
#define LOINV   3.0517578125e-5f   // 2^-15

__device__ __forceinline__ float fsigf(float x) {
    return __builtin_amdgcn_rcpf(1.f + __expf(-x));
}
__device__ __forceinline__ float ftanhf(float x) {
    return 1.f - 2.f * __builtin_amdgcn_rcpf(1.f + __expf(2.f * x));
}
__device__ __forceinline__ unsigned f2b(float f) {  // RNE f32->bf16 (finite)
    unsigned u = __float_as_uint(f);
    return (u + 0x7FFFu + ((u >> 16) & 1u)) >> 16;
}
__device__ __forceinline__ float blo(unsigned u) { return __uint_as_float(u << 16); }
__device__ __forceinline__ float bhi(unsigned u) { return __uint_as_float(u & 0xFFFF0000u); }
// f2b-based split: compiler-friendly (values can migrate to AGPRs).
__device__ __forceinline__ void splitf8(const float* __restrict__ p, short8_t& hi, short8_t& lo) {
    float4_t a = *(const float4_t*)p;
    float4_t b = *(const float4_t*)(p + 4);
#pragma unroll
    for (int j = 0; j < 8; ++j) {
        float x = j < 4 ? a[j] : b[j - 4];
        unsigned hb = f2b(x);
        float hf = __uint_as_float(hb << 16);
        unsigned lb = f2b(x - hf);
        hi[j] = (short)hb;
        lo[j] = (short)lb;
    }
}
// packed f32 pair -> 2x bf16 (inline asm: ONLY transient values in
// low-pressure kernels; never in lstm_comb).
__device__ __forceinline__ unsigned cvtpk(float lo, float hi) {
    unsigned r;
    asm("v_cvt_pk_bf16_f32 %0, %1, %2" : "=v"(r) : "v"(lo), "v"(hi));
    return r;
}
__device__ __forceinline__ void splitf8_pk(const float* __restrict__ p, short8_t& hi, short8_t& lo) {
    float4_t a = *(const float4_t*)p;
    float4_t b = *(const float4_t*)(p + 4);
    unsigned h0 = cvtpk(a[0], a[1]), h1 = cvtpk(a[2], a[3]);
    unsigned h2 = cvtpk(b[0], b[1]), h3 = cvtpk(b[2], b[3]);
    unsigned l0 = cvtpk(a[0] - blo(h0), a[1] - bhi(h0));
    unsigned l1 = cvtpk(a[2] - blo(h1), a[3] - bhi(h1));
    unsigned l2 = cvtpk(b[0] - blo(h2), b[1] - bhi(h2));
    unsigned l3 = cvtpk(b[2] - blo(h3), b[3] - bhi(h3));
    union { uint4_t u; short8_t s; } ch, cl;
    ch.u = (uint4_t){h0, h1, h2, h3};
    cl.u = (uint4_t){l0, l1, l2, l3};
    hi = ch.s;
    lo = cl.s;
}
// fp32[8] -> bf16x8 (plain cast, head path)
__device__ __forceinline__ short8_t cvtb8(const float* __restrict__ p) {
    float4_t a = *(const float4_t*)p;
    float4_t b = *(const float4_t*)(p + 4);
    union { uint4_t u; short8_t s; } c;
    c.u = (uint4_t){cvtpk(a[0], a[1]), cvtpk(a[2], a[3]),
                    cvtpk(b[0], b[1]), cvtpk(b[2], b[3])};
    return c.s;
}

// ===========================================================================
// ============================ fp32-X fast path =============================
// ===========================================================================

// ---------------------------------------------------------------------------
// X = h @ Wih.T + b, split-bf16 3-MFMA, stored fp32 in j-group-interleaved
// layout: element c = g*128+j at node*512 + (j>>2)*16 + g*4 + (j&3).
// ---------------------------------------------------------------------------
__global__ __launch_bounds__(256) void xgemm_f32(
    const float* __restrict__ A, const float* __restrict__ B,
    const float* __restrict__ bias, float* __restrict__ Xf)
{
    const int tid  = threadIdx.x;
    const int wave = tid >> 6, lane = tid & 63;
    const int l15  = lane & 15, quad = lane >> 4;
    const int r0   = blockIdx.y * 64 + wave * 16;
    const int c0   = blockIdx.x * 64;

    int arow = r0 + l15;
    if (arow >= NNODES) arow = NNODES - 1;

    float4_t acc[4];
#pragma unroll
    for (int ct = 0; ct < 4; ++ct) acc[ct] = (float4_t){0.f, 0.f, 0.f, 0.f};

#pragma unroll
    for (int kc = 0; kc < 4; ++kc) {
        const int kk = kc * 32 + quad * 8;
        short8_t ah, al;
        splitf8_pk(A + (size_t)arow * 128 + kk, ah, al);
#pragma unroll
        for (int ct = 0; ct < 4; ++ct) {
            short8_t bh, bl;
            splitf8_pk(B + (size_t)(c0 + ct * 16 + l15) * 128 + kk, bh, bl);
            acc[ct] = __builtin_amdgcn_mfma_f32_16x16x32_bf16(ah, bh, acc[ct], 0, 0, 0);
            acc[ct] = __builtin_amdgcn_mfma_f32_16x16x32_bf16(ah, bl, acc[ct], 0, 0, 0);
            acc[ct] = __builtin_amdgcn_mfma_f32_16x16x32_bf16(al, bh, acc[ct], 0, 0, 0);
        }
    }

#pragma unroll
    for (int ct = 0; ct < 4; ++ct) {
        int c = c0 + ct * 16 + l15;
        float bb = bias[c];
        const int jj = c & 127, gg = c >> 7;
        const int slot = (jj >> 2) * 16 + gg * 4 + (jj & 3);
#pragma unroll
        for (int r = 0; r < 4; ++r) {
            int rowo = r0 + quad * 4 + r;
            if (rowo < NNODES)
                Xf[(size_t)rowo * 512 + slot] = acc[ct][r] + bb;
        }
    }
}

// ---------------------------------------------------------------------------
// Fused 16-step LSTM + combine, fp32 X. Structure = R12/R9 (no spill):
// block 64 nodes, 512 thr (8 waves), wave owns j-slice [16w,16w+16) all
// 4 gates; hs double-buffered bf16 hi/lo LDS planes, 1 barrier/step.
// X: per lane/nt one 64B contiguous run (4x float4); xA/xB double-buffer,
// re-issued right after consumption (issue->use >= 1 GEMM+ACT).
// ---------------------------------------------------------------------------
__global__ __launch_bounds__(512, 2) void lstm_comb_f32(
    const float* __restrict__ Xf,
    const int* __restrict__ nbr, const float* __restrict__ Whh,
    const float* hin, const float* __restrict__ Ws,
    const float* __restrict__ Wn, const float* __restrict__ bs,
    const float* __restrict__ bn, float* hout)
{
    __shared__ short hsAhi[64 * 136], hsAlo[64 * 136];
    __shared__ short hsBhi[64 * 136], hsBlo[64 * 136];
    __shared__ int   nbrs[64 * 17];

    const int tid  = threadIdx.x;
    const int wave = tid >> 6, lane = tid & 63;
    const int l15  = lane & 15, quad = lane >> 4;
    const int n0   = blockIdx.x * 64;
    const int jb   = wave * 16;
    const int xoff = jb * 4 + quad * 16;   // float offset of this lane's 16-value run

    for (int i = tid; i < 64 * 136 / 2; i += 512) {
        ((unsigned*)hsAhi)[i] = 0;
        ((unsigned*)hsAlo)[i] = 0;
    }
    for (int i = tid; i < 64 * DNB; i += 512) {
        int node = n0 + (i >> 4);
        if (node >= NNODES) node = NNODES - 1;
        nbrs[(i >> 4) * 17 + (i & 15)] = nbr[node * DNB + (i & 15)];
    }

    // Whh split fragments: 4 gates x 4 k-chunks x (hi,lo) = 32 frags
    short8_t whi[4][4], wlo[4][4];
#pragma unroll
    for (int g = 0; g < 4; ++g)
#pragma unroll
        for (int kc = 0; kc < 4; ++kc)
            splitf8(Whh + (size_t)(g * 128 + jb + l15) * 128 + kc * 32 + quad * 8,
                    whi[g][kc], wlo[g][kc]);

    float cs[4][4], nh[4][4];
#pragma unroll
    for (int a = 0; a < 4; ++a)
#pragma unroll
        for (int b = 0; b < 4; ++b) { cs[a][b] = 0.f; nh[a][b] = 0.f; }

    __syncthreads();

#define XLOAD(XB, nt, T)                                                            \
    {                                                                               \
        int gi = nbrs[((nt) * 16 + l15) * 17 + (T)];                                \
        const float* xp = Xf + (size_t)gi * 512 + xoff;                             \
        XB[0] = *(const float4_t*)(xp);                                             \
        XB[1] = *(const float4_t*)(xp + 4);                                         \
        XB[2] = *(const float4_t*)(xp + 8);                                         \
        XB[3] = *(const float4_t*)(xp + 12);                                        \
    }

#define GEMMNT(nt, rdHi, rdLo)                                                      \
    {                                                                               \
        short8_t hfh[4], hfl[4];                                                    \
        _Pragma("unroll")                                                           \
        for (int kc = 0; kc < 4; ++kc) {                                            \
            hfh[kc] = *(const short8_t*)&(rdHi)[((nt) * 16 + l15) * 136 + kc * 32 + quad * 8]; \
            hfl[kc] = *(const short8_t*)&(rdLo)[((nt) * 16 + l15) * 136 + kc * 32 + quad * 8]; \
        }                                                                           \
        _Pragma("unroll")                                                           \
        for (int g = 0; g < 4; ++g) {                                               \
            float4_t a = (float4_t){0.f, 0.f, 0.f, 0.f};                            \
            _Pragma("unroll")                                                       \
            for (int kc = 0; kc < 4; ++kc) {                                        \
                a = __builtin_amdgcn_mfma_f32_16x16x32_bf16(whi[g][kc], hfh[kc], a, 0, 0, 0); \
                a = __builtin_amdgcn_mfma_f32_16x16x32_bf16(whi[g][kc], hfl[kc], a, 0, 0, 0); \
                a = __builtin_amdgcn_mfma_f32_16x16x32_bf16(wlo[g][kc], hfh[kc], a, 0, 0, 0); \
            }                                                                       \
            ac[g] = a;                                                              \
        }                                                                           \
    }

#define ACTF(nt, XB)                                                                \
    _Pragma("unroll")                                                               \
    for (int r = 0; r < 4; ++r) {                                                   \
        float iv = ac[0][r] + XB[0][r];                                             \
        float fv = ac[1][r] + XB[1][r];                                             \
        float gv = ac[2][r] + XB[2][r];                                             \
        float ov = ac[3][r] + XB[3][r];                                             \
        float c = fsigf(fv) * cs[nt][r] + fsigf(iv) * ftanhf(gv);                   \
        cs[nt][r] = c;                                                              \
        nh[nt][r] = fsigf(ov) * ftanhf(c);                                          \
    }

#define LSTM_STEP(rdHi, rdLo, wrHi, wrLo, T)                                        \
    {                                                                               \
        float4_t xA[4], xB[4], ac[4];                                               \
        XLOAD(xA, 0, T)                                                             \
        XLOAD(xB, 1, T)                                                             \
        GEMMNT(0, rdHi, rdLo) ACTF(0, xA)                                           \
        XLOAD(xA, 2, T)                                                             \
        GEMMNT(1, rdHi, rdLo) ACTF(1, xB)                                           \
        XLOAD(xB, 3, T)                                                             \
        GEMMNT(2, rdHi, rdLo) ACTF(2, xA)                                           \
        GEMMNT(3, rdHi, rdLo) ACTF(3, xB)                                           \
        _Pragma("unroll")                                                           \
        for (int nt = 0; nt < 4; ++nt) {                                            \
            unsigned hb[4], lb[4];                                                  \
            _Pragma("unroll")                                                       \
            for (int r = 0; r < 4; ++r) {                                           \
                float v = nh[nt][r];                                                \
                hb[r] = f2b(v);                                                     \
                lb[r] = f2b(v - __uint_as_float(hb[r] << 16));                      \
            }                                                                       \
            uint2 ph, pl;                                                           \
            ph.x = hb[0] | (hb[1] << 16); ph.y = hb[2] | (hb[3] << 16);             \
            pl.x = lb[0] | (lb[1] << 16); pl.y = lb[2] | (lb[3] << 16);             \
            const int o = (nt * 16 + l15) * 136 + jb + quad * 4;                    \
            *(uint2*)&(wrHi)[o] = ph;                                               \
            *(uint2*)&(wrLo)[o] = pl;                                               \
        }                                                                           \
        __syncthreads();                                                            \
    }

    for (int tp = 0; tp < 8; ++tp) {
        LSTM_STEP(hsAhi, hsAlo, hsBhi, hsBlo, 2 * tp);      // even t: read A write B
        LSTM_STEP(hsBhi, hsBlo, hsAhi, hsAlo, 2 * tp + 1);  // odd  t: read B write A
    }
#undef LSTM_STEP
#undef ACTF
#undef GEMMNT
#undef XLOAD
    // t=15 (odd) wrote A planes -> h_neigh lives in hsA.

    // ---- fused combine: h' = relu(hin@Ws.T + hn@Wn.T + bs + bn) ----
    const int ng = wave & 3, ch = wave >> 2;
    const int nodeA = n0 + ng * 16 + l15;
    const int nclA  = nodeA < NNODES ? nodeA : NNODES - 1;
    short8_t ahh[4], ahl[4], anh[4], anl[4];
#pragma unroll
    for (int kc = 0; kc < 4; ++kc) {
        splitf8(hin + (size_t)nclA * 128 + kc * 32 + quad * 8, ahh[kc], ahl[kc]);
        anh[kc] = *(const short8_t*)&hsAhi[(ng * 16 + l15) * 136 + kc * 32 + quad * 8];
        anl[kc] = *(const short8_t*)&hsAlo[(ng * 16 + l15) * 136 + kc * 32 + quad * 8];
    }
    __syncthreads();   // all hin reads done before any in-place store

#pragma unroll
    for (int ct = 0; ct < 4; ++ct) {
        const int ctg = ch * 4 + ct;
        float4_t acc = (float4_t){0.f, 0.f, 0.f, 0.f};
#pragma unroll
        for (int kc = 0; kc < 4; ++kc) {
            const int kk = kc * 32 + quad * 8;
            short8_t bh, bl;
            splitf8(Ws + (size_t)(ctg * 16 + l15) * 128 + kk, bh, bl);
            acc = __builtin_amdgcn_mfma_f32_16x16x32_bf16(ahh[kc], bh, acc, 0, 0, 0);
            acc = __builtin_amdgcn_mfma_f32_16x16x32_bf16(ahh[kc], bl, acc, 0, 0, 0);
            acc = __builtin_amdgcn_mfma_f32_16x16x32_bf16(ahl[kc], bh, acc, 0, 0, 0);
            splitf8(Wn + (size_t)(ctg * 16 + l15) * 128 + kk, bh, bl);
            acc = __builtin_amdgcn_mfma_f32_16x16x32_bf16(anh[kc], bh, acc, 0, 0, 0);
            acc = __builtin_amdgcn_mfma_f32_16x16x32_bf16(anh[kc], bl, acc, 0, 0, 0);
            acc = __builtin_amdgcn_mfma_f32_16x16x32_bf16(anl[kc], bh, acc, 0, 0, 0);
        }
        const int c = ctg * 16 + l15;
        const float bb = bs[c] + bn[c];
#pragma unroll
        for (int r = 0; r < 4; ++r) {
            int rowo = n0 + ng * 16 + quad * 4 + r;
            if (rowo < NNODES) {
                float v = acc[r] + bb;
                hout[(size_t)rowo * 128 + c] = v > 0.f ? v : 0.f;
            }
        }
    }
}

// ===========================================================================
// ===================== fallback path (R12, 3B/elem X) ======================
// ===========================================================================

__global__ __launch_bounds__(256) void xgemm_split(
    const float* __restrict__ A, const float* __restrict__ B,
    const float* __restrict__ bias, _Float16* __restrict__ Chi,
    char* __restrict__ Clo)
{
    const int tid  = threadIdx.x;
    const int wave = tid >> 6, lane = tid & 63;
    const int l15  = lane & 15, quad = lane >> 4;
    const int r0   = blockIdx.y * 64 + wave * 16;
    const int c0   = blockIdx.x * 64;

    int arow = r0 + l15;
    if (arow >= NNODES) arow = NNODES - 1;

    float4_t acc[4];
#pragma unroll
    for (int ct = 0; ct < 4; ++ct) acc[ct] = (float4_t){0.f, 0.f, 0.f, 0.f};

#pragma unroll
    for (int kc = 0; kc < 4; ++kc) {
        const int kk = kc * 32 + quad * 8;
        short8_t ah, al;
        splitf8_pk(A + (size_t)arow * 128 + kk, ah, al);
#pragma unroll
        for (int ct = 0; ct < 4; ++ct) {
            short8_t bh, bl;
            splitf8_pk(B + (size_t)(c0 + ct * 16 + l15) * 128 + kk, bh, bl);
            acc[ct] = __builtin_amdgcn_mfma_f32_16x16x32_bf16(ah, bh, acc[ct], 0, 0, 0);
            acc[ct] = __builtin_amdgcn_mfma_f32_16x16x32_bf16(ah, bl, acc[ct], 0, 0, 0);
            acc[ct] = __builtin_amdgcn_mfma_f32_16x16x32_bf16(al, bh, acc[ct], 0, 0, 0);
        }
    }

#pragma unroll
    for (int ct = 0; ct < 4; ++ct) {
        int c = c0 + ct * 16 + l15;
        float bb = bias[c];
        const int jj = c & 127, gg = c >> 7;          // gate-interleaved slot
#pragma unroll
        for (int r = 0; r < 4; ++r) {
            int rowo = r0 + quad * 4 + r;
            if (rowo < NNODES) {
                float v = acc[ct][r] + bb;
                _Float16 hi = (_Float16)v;
                float res = v - (float)hi;
                int q = (int)rintf(res * LOSCALE);
                q = q > 127 ? 127 : (q < -127 ? -127 : q);
                Chi[(size_t)rowo * 512 + jj * 4 + gg] = hi;
                Clo[(size_t)rowo * 512 + jj * 4 + gg] = (char)q;
            }
        }
    }
}

__global__ __launch_bounds__(512, 2) void lstm_comb(
    const _Float16* __restrict__ Xhi, const char* __restrict__ Xlo,
    const int* __restrict__ nbr, const float* __restrict__ Whh,
    const float* hin, const float* __restrict__ Ws,
    const float* __restrict__ Wn, const float* __restrict__ bs,
    const float* __restrict__ bn, float* hout)
{
    __shared__ short hsAhi[64 * 136], hsAlo[64 * 136];
    __shared__ short hsBhi[64 * 136], hsBlo[64 * 136];
    __shared__ int   nbrs[64 * 17];

    const int tid  = threadIdx.x;
    const int wave = tid >> 6, lane = tid & 63;
    const int l15  = lane & 15, quad = lane >> 4;
    const int n0   = blockIdx.x * 64;
    const int jb   = wave * 16;
    const int xoff = jb * 4 + quad * 16;

    for (int i = tid; i < 64 * 136 / 2; i += 512) {
        ((unsigned*)hsAhi)[i] = 0;
        ((unsigned*)hsAlo)[i] = 0;
    }
    for (int i = tid; i < 64 * DNB; i += 512) {
        int node = n0 + (i >> 4);
        if (node >= NNODES) node = NNODES - 1;
        nbrs[(i >> 4) * 17 + (i & 15)] = nbr[node * DNB + (i & 15)];
    }

    short8_t whi[4][4], wlo[4][4];
#pragma unroll
    for (int g = 0; g < 4; ++g)
#pragma unroll
        for (int kc = 0; kc < 4; ++kc)
            splitf8(Whh + (size_t)(g * 128 + jb + l15) * 128 + kc * 32 + quad * 8,
                    whi[g][kc], wlo[g][kc]);

    float cs[4][4], nh[4][4];
#pragma unroll
    for (int a = 0; a < 4; ++a)
#pragma unroll
        for (int b = 0; b < 4; ++b) { cs[a][b] = 0.f; nh[a][b] = 0.f; }

    __syncthreads();

#define XV(nt, r, g)                                                                \
    ((float)(((r) * 4 + (g)) < 8 ? xh0[nt][(r) * 4 + (g)] : xh1[nt][(r) * 4 + (g) - 8]) \
     + (float)((signed char)(xl4[nt][(r)] >> ((g) * 8))) * LOINV)

#define LSTM_STEP(rdHi, rdLo, wrHi, wrLo, T)                                        \
    {                                                                               \
        half8_t xh0[4], xh1[4]; uint4_t xl4[4];                                     \
        _Pragma("unroll")                                                           \
        for (int nt = 0; nt < 4; ++nt) {                                            \
            int gi = nbrs[(nt * 16 + l15) * 17 + (T)];                              \
            size_t xb = (size_t)gi * 512 + xoff;                                    \
            xh0[nt] = *(const half8_t*)(Xhi + xb);                                  \
            xh1[nt] = *(const half8_t*)(Xhi + xb + 8);                              \
            xl4[nt] = *(const uint4_t*)(Xlo + xb);                                  \
        }                                                                           \
        _Pragma("unroll")                                                           \
        for (int nt = 0; nt < 4; ++nt) {                                            \
            short8_t hfh[4], hfl[4];                                                \
            _Pragma("unroll")                                                       \
            for (int kc = 0; kc < 4; ++kc) {                                        \
                hfh[kc] = *(const short8_t*)&(rdHi)[(nt * 16 + l15) * 136 + kc * 32 + quad * 8]; \
                hfl[kc] = *(const short8_t*)&(rdLo)[(nt * 16 + l15) * 136 + kc * 32 + quad * 8]; \
            }                                                                       \
            float4_t ac[4];                                                         \
            _Pragma("unroll")                                                       \
            for (int g = 0; g < 4; ++g) {                                           \
                float4_t a = (float4_t){0.f, 0.f, 0.f, 0.f};                        \
                _Pragma("unroll")                                                   \
                for (int kc = 0; kc < 4; ++kc) {                                    \
                    a = __builtin_amdgcn_mfma_f32_16x16x32_bf16(whi[g][kc], hfh[kc], a, 0, 0, 0); \
                    a = __builtin_amdgcn_mfma_f32_16x16x32_bf16(whi[g][kc], hfl[kc], a, 0, 0, 0); \
                    a = __builtin_amdgcn_mfma_f32_16x16x32_bf16(wlo[g][kc], hfh[kc], a, 0, 0, 0); \
                }                                                                   \
                ac[g] = a;                                                          \
            }                                                                       \
            _Pragma("unroll")                                                       \
            for (int r = 0; r < 4; ++r) {                                           \
                float iv = ac[0][r] + XV(nt, r, 0);                                 \
                float fv = ac[1][r] + XV(nt, r, 1);                                 \
                float gv = ac[2][r] + XV(nt, r, 2);                                 \
                float ov = ac[3][r] + XV(nt, r, 3);                                 \
                float c = fsigf(fv) * cs[nt][r] + fsigf(iv) * ftanhf(gv);           \
                cs[nt][r] = c;                                                      \
                nh[nt][r] = fsigf(ov) * ftanhf(c);                                  \
            }                                                                       \
        }                                                                           \
        _Pragma("unroll")                                                           \
        for (int nt = 0; nt < 4; ++nt) {                                            \
            unsigned hb[4], lb[4];                                                  \
            _Pragma("unroll")                                                       \
            for (int r = 0; r < 4; ++r) {                                           \
                float v = nh[nt][r];                                                \
                hb[r] = f2b(v);                                                     \
                lb[r] = f2b(v - __uint_as_float(hb[r] << 16));                      \
            }                                                                       \
            uint2 ph, pl;                                                           \
            ph.x = hb[0] | (hb[1] << 16); ph.y = hb[2] | (hb[3] << 16);             \
            pl.x = lb[0] | (lb[1] << 16); pl.y = lb[2] | (lb[3] << 16);             \
            const int o = (nt * 16 + l15) * 136 + jb + quad * 4;                    \
            *(uint2*)&(wrHi)[o] = ph;                                               \
            *(uint2*)&(wrLo)[o] = pl;                                               \
        }                                                                           \
        __syncthreads();                                                            \
    }

    for (int tp = 0; tp < 8; ++tp) {
        LSTM_STEP(hsAhi, hsAlo, hsBhi, hsBlo, 2 * tp);
        LSTM_STEP(hsBhi, hsBlo, hsAhi, hsAlo, 2 * tp + 1);
    }
#undef LSTM_STEP
#undef XV

    const int ng = wave & 3, ch = wave >> 2;
    const int nodeA = n0 + ng * 16 + l15;
    const int nclA  = nodeA < NNODES ? nodeA : NNODES - 1;
    short8_t ahh[4], ahl[4], anh[4], anl[4];
#pragma unroll
    for (int kc = 0; kc < 4; ++kc) {
        splitf8(hin + (size_t)nclA * 128 + kc * 32 + quad * 8, ahh[kc], ahl[kc]);
        anh[kc] = *(const short8_t*)&hsAhi[(ng * 16 + l15) * 136 + kc * 32 + quad * 8];
        anl[kc] = *(const short8_t*)&hsAlo[(ng * 16 + l15) * 136 + kc * 32 + quad * 8];
    }
    __syncthreads();

#pragma unroll
    for (int ct = 0; ct < 4; ++ct) {
        const int ctg = ch * 4 + ct;
        float4_t acc = (float4_t){0.f, 0.f, 0.f, 0.f};
#pragma unroll
        for (int kc = 0; kc < 4; ++kc) {
            const int kk = kc * 32 + quad * 8;
            short8_t bh, bl;
            splitf8(Ws + (size_t)(ctg * 16 + l15) * 128 + kk, bh, bl);
            acc = __builtin_amdgcn_mfma_f32_16x16x32_bf16(ahh[kc], bh, acc, 0, 0, 0);
            acc = __builtin_amdgcn_mfma_f32_16x16x32_bf16(ahh[kc], bl, acc, 0, 0, 0);
            acc = __builtin_amdgcn_mfma_f32_16x16x32_bf16(ahl[kc], bh, acc, 0, 0, 0);
            splitf8(Wn + (size_t)(ctg * 16 + l15) * 128 + kk, bh, bl);
            acc = __builtin_amdgcn_mfma_f32_16x16x32_bf16(anh[kc], bh, acc, 0, 0, 0);
            acc = __builtin_amdgcn_mfma_f32_16x16x32_bf16(anh[kc], bl, acc, 0, 0, 0);
            acc = __builtin_amdgcn_mfma_f32_16x16x32_bf16(anl[kc], bh, acc, 0, 0, 0);
        }
        const int c = ctg * 16 + l15;
        const float bb = bs[c] + bn[c];
#pragma unroll
        for (int r = 0; r < 4; ++r) {
            int rowo = n0 + ng * 16 + quad * 4 + r;
            if (rowo < NNODES) {
                float v = acc[r] + bb;
                hout[(size_t)rowo * 128 + c] = v > 0.f ? v : 0.f;
            }
        }
    }
}

// ---------------------------------------------------------------------------
// Fused MLP heads (unchanged from R12).
// ---------------------------------------------------------------------------
__global__ __launch_bounds__(256) void heads_fused(
    const float* __restrict__ hsrc,
    const float* __restrict__ clsW, const float* __restrict__ clsb,
    const float* __restrict__ clsoW, const float* __restrict__ clsob,
    const float* __restrict__ cnfW, const float* __restrict__ cnfb,
    const float* __restrict__ cnfoW, const float* __restrict__ cnfob,
    float* __restrict__ oC, float* __restrict__ oL)
{
    __shared__ short xb[64 * 132];    // activations (bf16)
    __shared__ short wb[128 * 132];   // current layer weights (bf16)

    const int tid  = threadIdx.x;
    const int wave = tid >> 6, lane = tid & 63;
    const int l15  = lane & 15, quad = lane >> 4;
    const int n0   = blockIdx.x * 64;

    {
        int row = tid >> 2, cb = (tid & 3) * 32;
        int rsrc = n0 + row; if (rsrc >= NNODES) rsrc = NNODES - 1;
        const float* src = hsrc + (size_t)rsrc * 128 + cb;
#pragma unroll
        for (int i = 0; i < 4; ++i)
            *(short8_t*)&xb[row * 132 + cb + i * 8] = cvtb8(src + i * 8);
    }

    for (int head = 0; head < 2; ++head) {
        const float* W  = head ? cnfW : clsW;
        const float* bv = head ? cnfb : clsb;

        if (head == 1) {
            __syncthreads();
            int row = tid >> 2, cb = (tid & 3) * 32;
            int rsrc = n0 + row; if (rsrc >= NNODES) rsrc = NNODES - 1;
            const float* src = hsrc + (size_t)rsrc * 128 + cb;
#pragma unroll
            for (int i = 0; i < 4; ++i)
                *(short8_t*)&xb[row * 132 + cb + i * 8] = cvtb8(src + i * 8);
        }

        for (int l = 0; l < 5; ++l) {
            __syncthreads();
            short8_t af[4];
#pragma unroll
            for (int kc = 0; kc < 4; ++kc)
                af[kc] = *(const short8_t*)&xb[(wave * 16 + l15) * 132 + kc * 32 + quad * 8];
            const float* Wl = W + (size_t)l * 16384;
#pragma unroll
            for (int i = 0; i < 8; ++i) {
                int e = i * 2048 + tid * 8;
                int r = e >> 7, c = e & 127;
                *(short8_t*)&wb[r * 132 + c] = cvtb8(Wl + e);
            }
            __syncthreads();
#pragma unroll
            for (int ct = 0; ct < 8; ++ct) {
                float4_t acc = (float4_t){0.f, 0.f, 0.f, 0.f};
#pragma unroll
                for (int kc = 0; kc < 4; ++kc) {
                    short8_t bf = *(const short8_t*)&wb[(ct * 16 + l15) * 132 + kc * 32 + quad * 8];
                    acc = __builtin_amdgcn_mfma_f32_16x16x32_bf16(af[kc], bf, acc, 0, 0, 0);
                }
                int c = ct * 16 + l15;
                float bb = bv[l * 128 + c];
#pragma unroll
                for (int r = 0; r < 4; ++r) {
                    float v = acc[r] + bb;
                    v = v > 0.f ? v : 0.f;
                    xb[(wave * 16 + quad * 4 + r) * 132 + c] = (short)f2b(v);
                }
            }
        }

        __syncthreads();
        short8_t af[4];
#pragma unroll
        for (int kc = 0; kc < 4; ++kc)
            af[kc] = *(const short8_t*)&xb[(wave * 16 + l15) * 132 + kc * 32 + quad * 8];
        if (head == 0) {
            int wr = l15 < 10 ? l15 : 9;
            float4_t acc = (float4_t){0.f, 0.f, 0.f, 0.f};
#pragma unroll
            for (int kc = 0; kc < 4; ++kc) {
                short8_t bh, bl;
                splitf8(clsoW + (size_t)wr * 128 + kc * 32 + quad * 8, bh, bl);
                acc = __builtin_amdgcn_mfma_f32_16x16x32_bf16(af[kc], bh, acc, 0, 0, 0);
                acc = __builtin_amdgcn_mfma_f32_16x16x32_bf16(af[kc], bl, acc, 0, 0, 0);
            }
            if (l15 < 10) {
                float bb = clsob[l15];
#pragma unroll
                for (int r = 0; r < 4; ++r) {
                    int row = n0 + wave * 16 + quad * 4 + r;
                    if (row < NNODES) oC[(size_t)row * 10 + l15] = acc[r] + bb;
                }
            }
        } else {
            float4_t acc = (float4_t){0.f, 0.f, 0.f, 0.f};
#pragma unroll
            for (int kc = 0; kc < 4; ++kc) {
                short8_t bh, bl;
                splitf8(cnfoW + kc * 32 + quad * 8, bh, bl);
                acc = __builtin_amdgcn_mfma_f32_16x16x32_bf16(af[kc], bh, acc, 0, 0, 0);
                acc = __builtin_amdgcn_mfma_f32_16x16x32_bf16(af[kc], bl, acc, 0, 0, 0);
            }
            if (l15 == 0) {
                float bb = cnfob[0];
#pragma unroll
                for (int r = 0; r < 4; ++r) {
                    int row = n0 + wave * 16 + quad * 4 + r;
                    if (row < NNODES) oL[row] = acc[r] + bb;
                }
            }
        }
    }
}

// ===========================================================================
extern "C" void kernel_launch(void* const* d_in, const int* in_sizes, int n_in,
                              void* d_out, int out_size, void* d_ws, size_t ws_size,
                              hipStream_t stream)
{
    const float* h0     = (const float*)d_in[0];
    const int*   nbr    = (const int*)d_in[1];
    const float* Wih    = (const float*)d_in[2];   // [2,512,128]
    const float* Whh    = (const float*)d_in[3];   // [2,512,128]
    const float* lb     = (const float*)d_in[4];   // [2,512]
    const float* Wself  = (const float*)d_in[5];   // [2,128,128]
    const float* bself  = (const float*)d_in[6];
    const float* Wneigh = (const float*)d_in[7];
    const float* bneigh = (const float*)d_in[8];
    const float* clsW   = (const float*)d_in[9];   // [5,128,128]
    const float* clsb   = (const float*)d_in[10];
    const float* clsoW  = (const float*)d_in[11];  // [10,128]
    const float* clsob  = (const float*)d_in[12];
    const float* cnfW   = (const float*)d_in[13];
    const float* cnfb   = (const float*)d_in[14];
    const float* cnfoW  = (const float*)d_in[15];  // [1,128]
    const float* cnfob  = (const float*)d_in[16];

    char* ws = (char*)d_ws;
    float* out = (float*)d_out;
    float* oC  = out;                   // [N,10]
    float* hO  = out + 1000000;         // [N,128]; h1/h2 live here
    float* oL  = out + 13800000;        // [N,1]

    dim3 gx(8, 1563);    // xgemm: cols fast, M=100000, NC=512
    dim3 gl(1563);       // lstm, 512 thr
    dim3 gf(1563);       // heads_fused, 256 thr

    if (ws_size >= 204800000ull) {
        // ---- fp32-X fast path ----
        float* Xf = (float*)ws;                    // [0, 204.8M)
        xgemm_f32<<<gx, dim3(256), 0, stream>>>(h0, Wih, lb, Xf);
        lstm_comb_f32<<<gl, dim3(512), 0, stream>>>(Xf, nbr, Whh, h0,
                                                    Wself, Wneigh, bself, bneigh, hO);
        xgemm_f32<<<gx, dim3(256), 0, stream>>>(hO, Wih + 65536, lb + 512, Xf);
        lstm_comb_f32<<<gl, dim3(512), 0, stream>>>(Xf, nbr, Whh + 65536, hO,
                                                    Wself + 16384, Wneigh + 16384,
                                                    bself + 128, bneigh + 128, hO);
    } else {
        // ---- R12 fallback (3B/elem X) ----
        _Float16* Xhi = (_Float16*)ws;             // [0, 102.4M)
        char*     Xlo = ws + 102400000;            // [102.4M, 153.6M)
        xgemm_split<<<gx, dim3(256), 0, stream>>>(h0, Wih, lb, Xhi, Xlo);
        lstm_comb<<<gl, dim3(512), 0, stream>>>(Xhi, Xlo, nbr, Whh, h0,
                                                Wself, Wneigh, bself, bneigh, hO);
        xgemm_split<<<gx, dim3(256), 0, stream>>>(hO, Wih + 65536, lb + 512, Xhi, Xlo);
        lstm_comb<<<gl, dim3(512), 0, stream>>>(Xhi, Xlo, nbr, Whh + 65536, hO,
                                                Wself + 16384, Wneigh + 16384,
                                                bself + 128, bneigh + 128, hO);
    }

    // ---- heads: one fused dispatch ----
    heads_fused<<<gf, dim3(256), 0, stream>>>(hO, clsW, clsb, clsoW, clsob,
                                              cnfW, cnfb, cnfoW, cnfob, oC, oL);
}

// Round 8
// 2910.634 us; speedup vs baseline: 1.3054x; 1.3054x over previous
//
#include <hip/hip_runtime.h>
#include <stdint.h>

// GNNCell: 2x SAGEConv(lstm) + 2 MLP heads. N=100000, D=16, H=128, fp32 I/O.
// R12 passed 2920 us (lstm 2x1155, WRITE 78MB, no spill; heads fused).
//     VALU 40.4 > MFMA 25.1 > HBM 14.7; occ = 8 waves/CU (VGPR128+AGPR128).
// R13 REGRESSED 3799: fp32 X spilled again (WRITE 867MB) + doubled gather
//     traffic (FETCH 2.48GB). Lesson: X format stays fp16+i8; no register
//     experiments in lstm_comb. Also: absmax == 2^-8 exactly even with
//     exact-fp32 X -> absmax is output-path dominated; recurrence has slack.
// R14: R12 revert + ONE surgical VALU cut: hs re-pack via truncation split
//     + v_perm_b32 byte-select packing (builtin, no asm, no reg pinning):
//     hi = trunc16(x) via byte-select, r = x - bhi(x) (exact), lo =
//     trunc16(r). 12 ops/nt vs ~48 -> ~144 fewer VALU ops/step. Reader
//     side format-identical (bf16 hi/lo planes).
// R15: identical resubmit of R14 — round 7 bench was an infra failure
//     ("container failed twice"), no kernel verdict. Perm selector and all
//     indices re-audited; diff vs passing R12 is compute-only.
// Precision: X fp16-hi + i8-lo(2^-15); recurrence split-bf16 3-MFMA with
// truncated-hi hs (lo-compensated, 2^-16); heads bf16.

typedef __attribute__((ext_vector_type(8))) short short8_t;
typedef __attribute__((ext_vector_type(4))) float float4_t;
typedef __attribute__((ext_vector_type(4))) unsigned uint4_t;
typedef _Float16 half8_t __attribute__((ext_vector_type(8)));

#define NNODES 100000
#define DNB 16
#define LOSCALE 32768.0f
#define LOINV   3.0517578125e-5f   // 2^-15

__device__ __forceinline__ float fsigf(float x) {
    return __builtin_amdgcn_rcpf(1.f + __expf(-x));
}
__device__ __forceinline__ float ftanhf(float x) {
    return 1.f - 2.f * __builtin_amdgcn_rcpf(1.f + __expf(2.f * x));
}
__device__ __forceinline__ unsigned f2b(float f) {  // RNE f32->bf16 (finite)
    unsigned u = __float_as_uint(f);
    return (u + 0x7FFFu + ((u >> 16) & 1u)) >> 16;
}
__device__ __forceinline__ float blo(unsigned u) { return __uint_as_float(u << 16); }
__device__ __forceinline__ float bhi(unsigned u) { return __uint_as_float(u & 0xFFFF0000u); }
// pack hi16(u0) | hi16(u1)<<16 in ONE v_perm_b32 (builtin -> no reg pinning)
__device__ __forceinline__ unsigned pkhi(unsigned u0, unsigned u1) {
    return __builtin_amdgcn_perm(u1, u0, 0x07060302u);
}
// f2b-based split: compiler-friendly (values can migrate to AGPRs).
__device__ __forceinline__ void splitf8(const float* __restrict__ p, short8_t& hi, short8_t& lo) {
    float4_t a = *(const float4_t*)p;
    float4_t b = *(const float4_t*)(p + 4);
#pragma unroll
    for (int j = 0; j < 8; ++j) {
        float x = j < 4 ? a[j] : b[j - 4];
        unsigned hb = f2b(x);
        float hf = __uint_as_float(hb << 16);
        unsigned lb = f2b(x - hf);
        hi[j] = (short)hb;
        lo[j] = (short)lb;
    }
}
// packed f32 pair -> 2x bf16 (inline asm: ONLY transient values in
// low-pressure kernels; never in lstm_comb).
__device__ __forceinline__ unsigned cvtpk(float lo, float hi) {
    unsigned r;
    asm("v_cvt_pk_bf16_f32 %0, %1, %2" : "=v"(r) : "v"(lo), "v"(hi));
    return r;
}
__device__ __forceinline__ void splitf8_pk(const float* __restrict__ p, short8_t& hi, short8_t& lo) {
    float4_t a = *(const float4_t*)p;
    float4_t b = *(const float4_t*)(p + 4);
    unsigned h0 = cvtpk(a[0], a[1]), h1 = cvtpk(a[2], a[3]);
    unsigned h2 = cvtpk(b[0], b[1]), h3 = cvtpk(b[2], b[3]);
    unsigned l0 = cvtpk(a[0] - blo(h0), a[1] - bhi(h0));
    unsigned l1 = cvtpk(a[2] - blo(h1), a[3] - bhi(h1));
    unsigned l2 = cvtpk(b[0] - blo(h2), b[1] - bhi(h2));
    unsigned l3 = cvtpk(b[2] - blo(h3), b[3] - bhi(h3));
    union { uint4_t u; short8_t s; } ch, cl;
    ch.u = (uint4_t){h0, h1, h2, h3};
    cl.u = (uint4_t){l0, l1, l2, l3};
    hi = ch.s;
    lo = cl.s;
}
// fp32[8] -> bf16x8 (plain cast, head path)
__device__ __forceinline__ short8_t cvtb8(const float* __restrict__ p) {
    float4_t a = *(const float4_t*)p;
    float4_t b = *(const float4_t*)(p + 4);
    union { uint4_t u; short8_t s; } c;
    c.u = (uint4_t){cvtpk(a[0], a[1]), cvtpk(a[2], a[3]),
                    cvtpk(b[0], b[1]), cvtpk(b[2], b[3])};
    return c.s;
}

// ---------------------------------------------------------------------------
// X = h @ Wih.T + b, split-bf16 3-MFMA (rel ~2^-16), stored fp16-hi + i8-lo.
// GATE-INTERLEAVED output: element c = g*128+j at node*512 + j*4 + g.
// ---------------------------------------------------------------------------
__global__ __launch_bounds__(256) void xgemm_split(
    const float* __restrict__ A, const float* __restrict__ B,
    const float* __restrict__ bias, _Float16* __restrict__ Chi,
    char* __restrict__ Clo)
{
    const int tid  = threadIdx.x;
    const int wave = tid >> 6, lane = tid & 63;
    const int l15  = lane & 15, quad = lane >> 4;
    const int r0   = blockIdx.y * 64 + wave * 16;
    const int c0   = blockIdx.x * 64;

    int arow = r0 + l15;
    if (arow >= NNODES) arow = NNODES - 1;

    float4_t acc[4];
#pragma unroll
    for (int ct = 0; ct < 4; ++ct) acc[ct] = (float4_t){0.f, 0.f, 0.f, 0.f};

#pragma unroll
    for (int kc = 0; kc < 4; ++kc) {
        const int kk = kc * 32 + quad * 8;
        short8_t ah, al;
        splitf8_pk(A + (size_t)arow * 128 + kk, ah, al);
#pragma unroll
        for (int ct = 0; ct < 4; ++ct) {
            short8_t bh, bl;
            splitf8_pk(B + (size_t)(c0 + ct * 16 + l15) * 128 + kk, bh, bl);
            acc[ct] = __builtin_amdgcn_mfma_f32_16x16x32_bf16(ah, bh, acc[ct], 0, 0, 0);
            acc[ct] = __builtin_amdgcn_mfma_f32_16x16x32_bf16(ah, bl, acc[ct], 0, 0, 0);
            acc[ct] = __builtin_amdgcn_mfma_f32_16x16x32_bf16(al, bh, acc[ct], 0, 0, 0);
        }
    }

#pragma unroll
    for (int ct = 0; ct < 4; ++ct) {
        int c = c0 + ct * 16 + l15;
        float bb = bias[c];
        const int jj = c & 127, gg = c >> 7;          // gate-interleaved slot
#pragma unroll
        for (int r = 0; r < 4; ++r) {
            int rowo = r0 + quad * 4 + r;
            if (rowo < NNODES) {
                float v = acc[ct][r] + bb;
                _Float16 hi = (_Float16)v;
                float res = v - (float)hi;
                int q = (int)rintf(res * LOSCALE);
                q = q > 127 ? 127 : (q < -127 ? -127 : q);
                Chi[(size_t)rowo * 512 + jj * 4 + gg] = hi;
                Clo[(size_t)rowo * 512 + jj * 4 + gg] = (char)q;
            }
        }
    }
}

// ---------------------------------------------------------------------------
// Fused 16-step LSTM + combine — R12/R9 structure (proven no-spill).
// Block = 64 nodes, 512 threads (8 waves); wave owns j-slice [16w,16w+16)
// for all 4 gates. hs double-buffered bf16 hi/lo LDS planes, 1 barrier/step.
// X gathers gate-interleaved 3x16B/lane/nt at step start, consumed after
// each nt's MFMA chain. nbr staged in LDS.
// hs re-pack: truncation split + v_perm packing (12 ops/nt, builtin only).
// ---------------------------------------------------------------------------
__global__ __launch_bounds__(512, 2) void lstm_comb(
    const _Float16* __restrict__ Xhi, const char* __restrict__ Xlo,
    const int* __restrict__ nbr, const float* __restrict__ Whh,
    const float* hin, const float* __restrict__ Ws,
    const float* __restrict__ Wn, const float* __restrict__ bs,
    const float* __restrict__ bn, float* hout)
{
    __shared__ short hsAhi[64 * 136], hsAlo[64 * 136];
    __shared__ short hsBhi[64 * 136], hsBlo[64 * 136];
    __shared__ int   nbrs[64 * 17];

    const int tid  = threadIdx.x;
    const int wave = tid >> 6, lane = tid & 63;
    const int l15  = lane & 15, quad = lane >> 4;
    const int n0   = blockIdx.x * 64;
    const int jb   = wave * 16;
    const int xoff = jb * 4 + quad * 16;   // gate-interleaved lane offset

    for (int i = tid; i < 64 * 136 / 2; i += 512) {
        ((unsigned*)hsAhi)[i] = 0;
        ((unsigned*)hsAlo)[i] = 0;
    }
    for (int i = tid; i < 64 * DNB; i += 512) {
        int node = n0 + (i >> 4);
        if (node >= NNODES) node = NNODES - 1;
        nbrs[(i >> 4) * 17 + (i & 15)] = nbr[node * DNB + (i & 15)];
    }

    // Whh split fragments: 4 gates x 4 k-chunks x (hi,lo) = 32 frags
    short8_t whi[4][4], wlo[4][4];
#pragma unroll
    for (int g = 0; g < 4; ++g)
#pragma unroll
        for (int kc = 0; kc < 4; ++kc)
            splitf8(Whh + (size_t)(g * 128 + jb + l15) * 128 + kc * 32 + quad * 8,
                    whi[g][kc], wlo[g][kc]);

    float cs[4][4], nh[4][4];
#pragma unroll
    for (int a = 0; a < 4; ++a)
#pragma unroll
        for (int b = 0; b < 4; ++b) { cs[a][b] = 0.f; nh[a][b] = 0.f; }

    __syncthreads();

// hi value (g,r) lives at vector slot r*4+g; lo byte g of word r.
#define XV(nt, r, g)                                                                \
    ((float)(((r) * 4 + (g)) < 8 ? xh0[nt][(r) * 4 + (g)] : xh1[nt][(r) * 4 + (g) - 8]) \
     + (float)((signed char)(xl4[nt][(r)] >> ((g) * 8))) * LOINV)

#define LSTM_STEP(rdHi, rdLo, wrHi, wrLo, T)                                        \
    {                                                                               \
        half8_t xh0[4], xh1[4]; uint4_t xl4[4];                                     \
        _Pragma("unroll")                                                           \
        for (int nt = 0; nt < 4; ++nt) {                                            \
            int gi = nbrs[(nt * 16 + l15) * 17 + (T)];                              \
            size_t xb = (size_t)gi * 512 + xoff;                                    \
            xh0[nt] = *(const half8_t*)(Xhi + xb);                                  \
            xh1[nt] = *(const half8_t*)(Xhi + xb + 8);                              \
            xl4[nt] = *(const uint4_t*)(Xlo + xb);                                  \
        }                                                                           \
        _Pragma("unroll")                                                           \
        for (int nt = 0; nt < 4; ++nt) {                                            \
            short8_t hfh[4], hfl[4];                                                \
            _Pragma("unroll")                                                       \
            for (int kc = 0; kc < 4; ++kc) {                                        \
                hfh[kc] = *(const short8_t*)&(rdHi)[(nt * 16 + l15) * 136 + kc * 32 + quad * 8]; \
                hfl[kc] = *(const short8_t*)&(rdLo)[(nt * 16 + l15) * 136 + kc * 32 + quad * 8]; \
            }                                                                       \
            float4_t ac[4];                                                         \
            _Pragma("unroll")                                                       \
            for (int g = 0; g < 4; ++g) {                                           \
                float4_t a = (float4_t){0.f, 0.f, 0.f, 0.f};                        \
                _Pragma("unroll")                                                   \
                for (int kc = 0; kc < 4; ++kc) {                                    \
                    a = __builtin_amdgcn_mfma_f32_16x16x32_bf16(whi[g][kc], hfh[kc], a, 0, 0, 0); \
                    a = __builtin_amdgcn_mfma_f32_16x16x32_bf16(whi[g][kc], hfl[kc], a, 0, 0, 0); \
                    a = __builtin_amdgcn_mfma_f32_16x16x32_bf16(wlo[g][kc], hfh[kc], a, 0, 0, 0); \
                }                                                                   \
                ac[g] = a;                                                          \
            }                                                                       \
            _Pragma("unroll")                                                       \
            for (int r = 0; r < 4; ++r) {                                           \
                float iv = ac[0][r] + XV(nt, r, 0);                                 \
                float fv = ac[1][r] + XV(nt, r, 1);                                 \
                float gv = ac[2][r] + XV(nt, r, 2);                                 \
                float ov = ac[3][r] + XV(nt, r, 3);                                 \
                float c = fsigf(fv) * cs[nt][r] + fsigf(iv) * ftanhf(gv);           \
                cs[nt][r] = c;                                                      \
                nh[nt][r] = fsigf(ov) * ftanhf(c);                                  \
            }                                                                       \
        }                                                                           \
        _Pragma("unroll")                                                           \
        for (int nt = 0; nt < 4; ++nt) {                                            \
            /* truncation split + v_perm pack: hi=trunc16(x), r=x-bhi(x), */        \
            /* lo=trunc16(r). 12 VALU ops vs ~48 for double-RNE f2b.      */        \
            unsigned u0 = __float_as_uint(nh[nt][0]);                               \
            unsigned u1 = __float_as_uint(nh[nt][1]);                               \
            unsigned u2 = __float_as_uint(nh[nt][2]);                               \
            unsigned u3 = __float_as_uint(nh[nt][3]);                               \
            unsigned r0 = __float_as_uint(nh[nt][0] - bhi(u0));                     \
            unsigned r1 = __float_as_uint(nh[nt][1] - bhi(u1));                     \
            unsigned r2 = __float_as_uint(nh[nt][2] - bhi(u2));                     \
            unsigned r3 = __float_as_uint(nh[nt][3] - bhi(u3));                     \
            uint2 ph, pl;                                                           \
            ph.x = pkhi(u0, u1); ph.y = pkhi(u2, u3);                               \
            pl.x = pkhi(r0, r1); pl.y = pkhi(r2, r3);                               \
            const int o = (nt * 16 + l15) * 136 + jb + quad * 4;                    \
            *(uint2*)&(wrHi)[o] = ph;                                               \
            *(uint2*)&(wrLo)[o] = pl;                                               \
        }                                                                           \
        __syncthreads();                                                            \
    }

    for (int tp = 0; tp < 8; ++tp) {
        LSTM_STEP(hsAhi, hsAlo, hsBhi, hsBlo, 2 * tp);      // even t: read A write B
        LSTM_STEP(hsBhi, hsBlo, hsAhi, hsAlo, 2 * tp + 1);  // odd  t: read B write A
    }
#undef LSTM_STEP
#undef XV
    // t=15 (odd) wrote A planes -> h_neigh lives in hsA.

    // ---- fused combine: h' = relu(hin@Ws.T + hn@Wn.T + bs + bn) ----
    const int ng = wave & 3, ch = wave >> 2;
    const int nodeA = n0 + ng * 16 + l15;
    const int nclA  = nodeA < NNODES ? nodeA : NNODES - 1;
    short8_t ahh[4], ahl[4], anh[4], anl[4];
#pragma unroll
    for (int kc = 0; kc < 4; ++kc) {
        splitf8(hin + (size_t)nclA * 128 + kc * 32 + quad * 8, ahh[kc], ahl[kc]);
        anh[kc] = *(const short8_t*)&hsAhi[(ng * 16 + l15) * 136 + kc * 32 + quad * 8];
        anl[kc] = *(const short8_t*)&hsAlo[(ng * 16 + l15) * 136 + kc * 32 + quad * 8];
    }
    __syncthreads();   // all hin reads done before any in-place store

#pragma unroll
    for (int ct = 0; ct < 4; ++ct) {
        const int ctg = ch * 4 + ct;
        float4_t acc = (float4_t){0.f, 0.f, 0.f, 0.f};
#pragma unroll
        for (int kc = 0; kc < 4; ++kc) {
            const int kk = kc * 32 + quad * 8;
            short8_t bh, bl;
            splitf8(Ws + (size_t)(ctg * 16 + l15) * 128 + kk, bh, bl);
            acc = __builtin_amdgcn_mfma_f32_16x16x32_bf16(ahh[kc], bh, acc, 0, 0, 0);
            acc = __builtin_amdgcn_mfma_f32_16x16x32_bf16(ahh[kc], bl, acc, 0, 0, 0);
            acc = __builtin_amdgcn_mfma_f32_16x16x32_bf16(ahl[kc], bh, acc, 0, 0, 0);
            splitf8(Wn + (size_t)(ctg * 16 + l15) * 128 + kk, bh, bl);
            acc = __builtin_amdgcn_mfma_f32_16x16x32_bf16(anh[kc], bh, acc, 0, 0, 0);
            acc = __builtin_amdgcn_mfma_f32_16x16x32_bf16(anh[kc], bl, acc, 0, 0, 0);
            acc = __builtin_amdgcn_mfma_f32_16x16x32_bf16(anl[kc], bh, acc, 0, 0, 0);
        }
        const int c = ctg * 16 + l15;
        const float bb = bs[c] + bn[c];
#pragma unroll
        for (int r = 0; r < 4; ++r) {
            int rowo = n0 + ng * 16 + quad * 4 + r;
            if (rowo < NNODES) {
                float v = acc[r] + bb;
                hout[(size_t)rowo * 128 + c] = v > 0.f ? v : 0.f;
            }
        }
    }
}

// ---------------------------------------------------------------------------
// Fused MLP heads (unchanged from R12).
// ---------------------------------------------------------------------------
__global__ __launch_bounds__(256) void heads_fused(
    const float* __restrict__ hsrc,
    const float* __restrict__ clsW, const float* __restrict__ clsb,
    const float* __restrict__ clsoW, const float* __restrict__ clsob,
    const float* __restrict__ cnfW, const float* __restrict__ cnfb,
    const float* __restrict__ cnfoW, const float* __restrict__ cnfob,
    float* __restrict__ oC, float* __restrict__ oL)
{
    __shared__ short xb[64 * 132];    // activations (bf16)
    __shared__ short wb[128 * 132];   // current layer weights (bf16)

    const int tid  = threadIdx.x;
    const int wave = tid >> 6, lane = tid & 63;
    const int l15  = lane & 15, quad = lane >> 4;
    const int n0   = blockIdx.x * 64;

    {
        int row = tid >> 2, cb = (tid & 3) * 32;
        int rsrc = n0 + row; if (rsrc >= NNODES) rsrc = NNODES - 1;
        const float* src = hsrc + (size_t)rsrc * 128 + cb;
#pragma unroll
        for (int i = 0; i < 4; ++i)
            *(short8_t*)&xb[row * 132 + cb + i * 8] = cvtb8(src + i * 8);
    }

    for (int head = 0; head < 2; ++head) {
        const float* W  = head ? cnfW : clsW;
        const float* bv = head ? cnfb : clsb;

        if (head == 1) {
            __syncthreads();
            int row = tid >> 2, cb = (tid & 3) * 32;
            int rsrc = n0 + row; if (rsrc >= NNODES) rsrc = NNODES - 1;
            const float* src = hsrc + (size_t)rsrc * 128 + cb;
#pragma unroll
            for (int i = 0; i < 4; ++i)
                *(short8_t*)&xb[row * 132 + cb + i * 8] = cvtb8(src + i * 8);
        }

        for (int l = 0; l < 5; ++l) {
            __syncthreads();
            short8_t af[4];
#pragma unroll
            for (int kc = 0; kc < 4; ++kc)
                af[kc] = *(const short8_t*)&xb[(wave * 16 + l15) * 132 + kc * 32 + quad * 8];
            const float* Wl = W + (size_t)l * 16384;
#pragma unroll
            for (int i = 0; i < 8; ++i) {
                int e = i * 2048 + tid * 8;
                int r = e >> 7, c = e & 127;
                *(short8_t*)&wb[r * 132 + c] = cvtb8(Wl + e);
            }
            __syncthreads();
#pragma unroll
            for (int ct = 0; ct < 8; ++ct) {
                float4_t acc = (float4_t){0.f, 0.f, 0.f, 0.f};
#pragma unroll
                for (int kc = 0; kc < 4; ++kc) {
                    short8_t bf = *(const short8_t*)&wb[(ct * 16 + l15) * 132 + kc * 32 + quad * 8];
                    acc = __builtin_amdgcn_mfma_f32_16x16x32_bf16(af[kc], bf, acc, 0, 0, 0);
                }
                int c = ct * 16 + l15;
                float bb = bv[l * 128 + c];
#pragma unroll
                for (int r = 0; r < 4; ++r) {
                    float v = acc[r] + bb;
                    v = v > 0.f ? v : 0.f;
                    xb[(wave * 16 + quad * 4 + r) * 132 + c] = (short)f2b(v);
                }
            }
        }

        __syncthreads();
        short8_t af[4];
#pragma unroll
        for (int kc = 0; kc < 4; ++kc)
            af[kc] = *(const short8_t*)&xb[(wave * 16 + l15) * 132 + kc * 32 + quad * 8];
        if (head == 0) {
            int wr = l15 < 10 ? l15 : 9;
            float4_t acc = (float4_t){0.f, 0.f, 0.f, 0.f};
#pragma unroll
            for (int kc = 0; kc < 4; ++kc) {
                short8_t bh, bl;
                splitf8(clsoW + (size_t)wr * 128 + kc * 32 + quad * 8, bh, bl);
                acc = __builtin_amdgcn_mfma_f32_16x16x32_bf16(af[kc], bh, acc, 0, 0, 0);
                acc = __builtin_amdgcn_mfma_f32_16x16x32_bf16(af[kc], bl, acc, 0, 0, 0);
            }
            if (l15 < 10) {
                float bb = clsob[l15];
#pragma unroll
                for (int r = 0; r < 4; ++r) {
                    int row = n0 + wave * 16 + quad * 4 + r;
                    if (row < NNODES) oC[(size_t)row * 10 + l15] = acc[r] + bb;
                }
            }
        } else {
            float4_t acc = (float4_t){0.f, 0.f, 0.f, 0.f};
#pragma unroll
            for (int kc = 0; kc < 4; ++kc) {
                short8_t bh, bl;
                splitf8(cnfoW + kc * 32 + quad * 8, bh, bl);
                acc = __builtin_amdgcn_mfma_f32_16x16x32_bf16(af[kc], bh, acc, 0, 0, 0);
                acc = __builtin_amdgcn_mfma_f32_16x16x32_bf16(af[kc], bl, acc, 0, 0, 0);
            }
            if (l15 == 0) {
                float bb = cnfob[0];
#pragma unroll
                for (int r = 0; r < 4; ++r) {
                    int row = n0 + wave * 16 + quad * 4 + r;
                    if (row < NNODES) oL[row] = acc[r] + bb;
                }
            }
        }
    }
}

// ===========================================================================
extern "C" void kernel_launch(void* const* d_in, const int* in_sizes, int n_in,
                              void* d_out, int out_size, void* d_ws, size_t ws_size,
                              hipStream_t stream)
{
    const float* h0     = (const float*)d_in[0];
    const int*   nbr    = (const int*)d_in[1];
    const float* Wih    = (const float*)d_in[2];   // [2,512,128]
    const float* Whh    = (const float*)d_in[3];   // [2,512,128]
    const float* lb     = (const float*)d_in[4];   // [2,512]
    const float* Wself  = (const float*)d_in[5];   // [2,128,128]
    const float* bself  = (const float*)d_in[6];
    const float* Wneigh = (const float*)d_in[7];
    const float* bneigh = (const float*)d_in[8];
    const float* clsW   = (const float*)d_in[9];   // [5,128,128]
    const float* clsb   = (const float*)d_in[10];
    const float* clsoW  = (const float*)d_in[11];  // [10,128]
    const float* clsob  = (const float*)d_in[12];
    const float* cnfW   = (const float*)d_in[13];
    const float* cnfb   = (const float*)d_in[14];
    const float* cnfoW  = (const float*)d_in[15];  // [1,128]
    const float* cnfob  = (const float*)d_in[16];

    char* ws = (char*)d_ws;
    _Float16* Xhi = (_Float16*)ws;                 // [0, 102.4M)
    char*     Xlo = ws + 102400000;                // [102.4M, 153.6M)

    float* out = (float*)d_out;
    float* oC  = out;                   // [N,10]
    float* hO  = out + 1000000;         // [N,128]; h1/h2 live here
    float* oL  = out + 13800000;        // [N,1]

    dim3 gx(8, 1563);    // xgemm: cols fast, M=100000, NC=512
    dim3 gl(1563);       // lstm, 512 thr
    dim3 gf(1563);       // heads_fused, 256 thr

    // ---- layer 1: h1 -> d_out h slot ----
    xgemm_split<<<gx, dim3(256), 0, stream>>>(h0, Wih, lb, Xhi, Xlo);
    lstm_comb<<<gl, dim3(512), 0, stream>>>(Xhi, Xlo, nbr, Whh, h0,
                                            Wself, Wneigh, bself, bneigh, hO);
    // ---- layer 2: h2 -> same slot, in-place ----
    xgemm_split<<<gx, dim3(256), 0, stream>>>(hO, Wih + 65536, lb + 512, Xhi, Xlo);
    lstm_comb<<<gl, dim3(512), 0, stream>>>(Xhi, Xlo, nbr, Whh + 65536, hO,
                                            Wself + 16384, Wneigh + 16384,
                                            bself + 128, bneigh + 128, hO);

    // ---- heads: one fused dispatch ----
    heads_fused<<<gf, dim3(256), 0, stream>>>(hO, clsW, clsb, clsoW, clsob,
                                              cnfW, cnfb, cnfoW, cnfob, oC, oL);
}